// Round 6
// baseline (216.796 us; speedup 1.0000x reference)
//
#include <hip/hip_runtime.h>
#include <hip/hip_bf16.h>

// ---------------------------------------------------------------------------
// GCN: h = relu(GCNConv(x,W1,b1)); x1 = relu(GCNConv(h,W2,b2));
//      x2 = meanpool(x1,batch); out = log_softmax(relu(x2@fc1+b)@fc2+b)
//
// R19: gather1 + gemm2 fused (h never materialized).
//  - g1g2_kernel: 512 thr, 16 nodes/block, both fp8 slices in one block
//    (32 lanes/node = 4 edge-lanes x 8 feature-groups; bucket staging and
//    cnt reads once instead of twice). h rows land in a 16x136 bf16 LDS
//    tile (same f2bf RNE as before -> bitwise-identical A-fragments);
//    waves 0-3 then do the 16x64 GEMM (4 MFMA each) vs LDS-staged wt2 and
//    pack fp8 with inline dinv. Saves hbf write+read (25.6 MB) + 1 dispatch.
//  - xw2f8 moved to a disjoint bufA region (it used to alias xw1f8; with
//    the fusion both are live at once).
//  - Keeps: R18 staged part, exclusive-range place, inline dinv, fused
//    pool in gather2, cnt-gated slot staging, weight-prep rider on part.
// ---------------------------------------------------------------------------

#define CAP 64
#define OVFCAP 8192
#define NRANGE 512   // exclusive ranges; == part scan width (threads/block)
#define MAXNRP 2048  // max nodes per range (LDS cursor arrays in place)
#define BSTR 68      // LDS bucket stride (words)
#define KP 136       // bf16 weight row stride (128 + 8 pad)
#define PARTNB 256   // edge-partition blocks (weight blocks follow)
#define PBUF 6400    // staged records per part block (>= ceil(E/PARTNB))

typedef float v2f  __attribute__((ext_vector_type(2)));
typedef float f32x4 __attribute__((ext_vector_type(4)));
typedef short bf16x8 __attribute__((ext_vector_type(8)));

__device__ inline unsigned short f2bf(float f) {   // fp32 -> bf16 RNE
    unsigned u = __float_as_uint(f);
    u += 0x7FFFu + ((u >> 16) & 1u);
    return (unsigned short)(u >> 16);
}
__device__ inline void fp8x4_to_f32(unsigned w, float* o) {
    v2f lo = __builtin_amdgcn_cvt_pk_f32_fp8((int)w, false);
    v2f hi = __builtin_amdgcn_cvt_pk_f32_fp8((int)w, true);
    o[0] = lo[0]; o[1] = lo[1]; o[2] = hi[0]; o[3] = hi[1];
}
__device__ inline unsigned f32x4_to_fp8(float a, float b, float c, float d) {
    int w = 0;
    w = __builtin_amdgcn_cvt_pk_fp8_f32(a, b, w, false);
    w = __builtin_amdgcn_cvt_pk_fp8_f32(c, d, w, true);
    return (unsigned)w;
}
__device__ inline float dinv_of(int ws) {          // deg^{-1/2} incl. self-loop
    return rsqrtf((float)ws * (1.0f / 32768.0f) + 1.0f);
}

// P1: partition edges into NRANGE per-range lists rng[r] of (col, row<<15|q15(ew)).
// In-LDS staged + coalesced flush. Blocks >= PARTNB do the weight transpose.
__global__ __launch_bounds__(512)
void part_kernel(const int* __restrict__ rows, const int* __restrict__ cols,
                 const float* __restrict__ ew, int* __restrict__ rangeCnt,
                 uint2* __restrict__ rng, int E, int NR, int RSEG,
                 const float* __restrict__ W1, const float* __restrict__ W2,
                 unsigned short* __restrict__ wt1, unsigned short* __restrict__ wt2) {
    const int t = threadIdx.x;
    if (blockIdx.x >= PARTNB) {               // weight prep: wt[c][k] = W[k][c] (bf16)
        if (blockIdx.x == PARTNB) {
            for (int i = t; i < 128 * 128; i += 512) {
                int c = i >> 7, k = i & 127;
                wt1[c * KP + k] = f2bf(W1[k * 128 + c]);
            }
        } else {
            for (int i = t; i < 64 * 128; i += 512) {
                int c = i >> 7, k = i & 127;
                wt2[c * KP + k] = f2bf(W2[k * 64 + c]);
            }
        }
        return;
    }
    __shared__ uint2 buf[PBUF];      // range-sorted staging (51.2 KB)
    __shared__ int hcnt[NRANGE];     // histogram, then scatter cursor
    __shared__ int lbase[NRANGE];    // local exclusive base
    __shared__ int gbase[NRANGE];    // reserved global base
    __shared__ int wtot[8];
    const int CS = (E + PARTNB - 1) / PARTNB;
    const int e0 = blockIdx.x * CS, e1 = min(e0 + CS, E);
    const int M = e1 - e0;

    if (CS <= PBUF) {
        // ---- staged path ----
        for (int i = t; i < NRANGE; i += 512) hcnt[i] = 0;
        __syncthreads();
        for (int e = e0 + t; e < e1; e += 512)
            atomicAdd(&hcnt[cols[e] / NR], 1);
        __syncthreads();
        {   // block-wide exclusive scan over the 512 range counts (1/thread)
            int v = hcnt[t];
            int inc = v;
            #pragma unroll
            for (int off = 1; off < 64; off <<= 1) {
                int n = __shfl_up(inc, off);
                if ((t & 63) >= off) inc += n;
            }
            const int w = t >> 6;
            if ((t & 63) == 63) wtot[w] = inc;
            __syncthreads();
            int wo = 0;
            for (int k = 0; k < w; ++k) wo += wtot[k];
            int excl = wo + inc - v;
            lbase[t] = excl;
            gbase[t] = (v > 0) ? atomicAdd(&rangeCnt[t], v) : 0;
            hcnt[t] = excl;              // becomes scatter cursor
        }
        __syncthreads();
        for (int e = e0 + t; e < e1; e += 512) {   // scatter into LDS by range
            int c = cols[e];
            int r = c / NR;
            int q = (int)(ew[e] * 32768.0f);
            if (q > 32767) q = 32767;
            unsigned rec = ((unsigned)rows[e] << 15) | (unsigned)q;
            int p = atomicAdd(&hcnt[r], 1);
            buf[p] = make_uint2((unsigned)c, rec);
        }
        __syncthreads();
        for (int i = t; i < M; i += 512) {         // coalesced flush
            uint2 u = buf[i];
            int r = (int)u.x / NR;
            int idx = gbase[r] + (i - lbase[r]);
            if (idx < RSEG) rng[(size_t)r * RSEG + idx] = u;
        }
    } else {
        // ---- fallback: direct scatter (R16 path) ----
        for (int i = t; i < NRANGE; i += 512) hcnt[i] = 0;
        __syncthreads();
        for (int e = e0 + t; e < e1; e += 512)
            atomicAdd(&hcnt[cols[e] / NR], 1);
        __syncthreads();
        for (int i = t; i < NRANGE; i += 512)
            hcnt[i] = atomicAdd(&rangeCnt[i], hcnt[i]);
        __syncthreads();
        for (int e = e0 + t; e < e1; e += 512) {
            int c = cols[e];
            int r = c / NR;
            int q = (int)(ew[e] * 32768.0f);
            if (q > 32767) q = 32767;
            unsigned rec = ((unsigned)rows[e] << 15) | (unsigned)q;
            int pos = atomicAdd(&hcnt[r], 1);
            if (pos < RSEG) rng[(size_t)r * RSEG + pos] = make_uint2((unsigned)c, rec);
        }
    }
}

// P2: block r exclusively owns range r -> LDS position cursors from 0.
// cnt/wsum are exact (deterministic) side products; no histogram/scan needed.
__global__ __launch_bounds__(512)
void place_kernel(const uint2* __restrict__ rng, const int* __restrict__ rangeCnt,
                  int* __restrict__ cnt, int* __restrict__ wsum,
                  unsigned* __restrict__ slot, int4* __restrict__ ovf,
                  int* __restrict__ ovfcnt, int NR, int RSEG, int N) {
    __shared__ int cur[MAXNRP];
    __shared__ int wsl[MAXNRP];
    const int r = blockIdx.x;
    const int t = threadIdx.x;
    const int n0 = r * NR;
    for (int n = t; n < NR; n += 512) { cur[n] = 0; wsl[n] = 0; }
    __syncthreads();
    const int M = min(rangeCnt[r], RSEG);
    const uint2* lst = rng + (size_t)r * RSEG;
    for (int k = t; k < M; k += 512) {
        uint2 u2 = lst[k];
        int cl = (int)u2.x - n0;
        int q = (int)(u2.y & 32767u);
        int pos = atomicAdd(&cur[cl], 1);
        atomicAdd(&wsl[cl], q);
        if (pos < CAP) {
            slot[(size_t)u2.x * CAP + pos] = u2.y;
        } else {
            int o = atomicAdd(ovfcnt, 1);
            if (o < OVFCAP)
                ovf[o] = make_int4((int)(u2.y >> 15), (int)u2.x, q, 0);
        }
    }
    __syncthreads();
    for (int n = t; n < NR; n += 512) {
        int gn = n0 + n;
        if (gn < N) { cnt[gn] = cur[n]; wsum[gn] = wsl[n]; }
    }
}

// Fallback for shapes the range partition can't handle (not taken here).
__global__ void place_simple_kernel(const int* __restrict__ rows, const int* __restrict__ cols,
                                    const float* __restrict__ ew, int* __restrict__ cnt,
                                    int* __restrict__ wsum,
                                    unsigned* __restrict__ slot, int4* __restrict__ ovf,
                                    int* __restrict__ ovfcnt, int E) {
    int e = blockIdx.x * 256 + threadIdx.x;
    if (e >= E) return;
    int r = rows[e], c = cols[e];
    int q = (int)(ew[e] * 32768.0f);
    if (q > 32767) q = 32767;
    int pos = atomicAdd(&cnt[c], 1);
    atomicAdd(&wsum[c], q);
    if (pos < CAP) {
        slot[(size_t)c * CAP + pos] = ((unsigned)r << 15) | (unsigned)q;
    } else {
        int o = atomicAdd(ovfcnt, 1);
        if (o < OVFCAP) ovf[o] = make_int4(r, c, q, 0);
    }
}

// MFMA bf16 GEMM -> fp8 sliced table. outf8[slice][M][64] = (A@W)*dinv[row].
template <int BN, bool AF32>
__global__ __launch_bounds__(256)
void gemm_mfma_kernel(const void* __restrict__ Av, const unsigned short* __restrict__ wt,
                      const int* __restrict__ wsum, unsigned char* __restrict__ outf8,
                      int M) {
    constexpr int CT = BN / 16;          // col tiles
    constexpr int EPS = BN + 4;          // epilogue LDS row stride (floats)
    __shared__ unsigned short wl[BN * KP];
    __shared__ float ep[4][16 * EPS];
    const int t = threadIdx.x;
    for (int i = t; i < BN * KP / 8; i += 256)
        ((uint4*)wl)[i] = ((const uint4*)wt)[i];
    __syncthreads();
    const int w = t >> 6, lane = t & 63;
    const int n16 = lane & 15, q = lane >> 4;
    const int rowBase = blockIdx.x * 64 + w * 16;
    int arow = rowBase + n16; if (arow >= M) arow = M - 1;
    f32x4 acc[CT];
    #pragma unroll
    for (int ct = 0; ct < CT; ++ct) acc[ct] = (f32x4){0.f, 0.f, 0.f, 0.f};
    #pragma unroll
    for (int kt = 0; kt < 4; ++kt) {
        bf16x8 af;
        if (AF32) {
            const float* ap = (const float*)Av + (size_t)arow * 128 + kt * 32 + q * 8;
            float4 a0 = *(const float4*)ap;
            float4 a1 = *(const float4*)(ap + 4);
            af[0] = (short)f2bf(a0.x); af[1] = (short)f2bf(a0.y);
            af[2] = (short)f2bf(a0.z); af[3] = (short)f2bf(a0.w);
            af[4] = (short)f2bf(a1.x); af[5] = (short)f2bf(a1.y);
            af[6] = (short)f2bf(a1.z); af[7] = (short)f2bf(a1.w);
        } else {
            af = *(const bf16x8*)((const unsigned short*)Av + (size_t)arow * 128 + kt * 32 + q * 8);
        }
        #pragma unroll
        for (int ct = 0; ct < CT; ++ct) {
            bf16x8 bfr = *(const bf16x8*)&wl[(ct * 16 + n16) * KP + kt * 32 + q * 8];
            acc[ct] = __builtin_amdgcn_mfma_f32_16x16x32_bf16(af, bfr, acc[ct], 0, 0, 0);
        }
    }
    #pragma unroll
    for (int ct = 0; ct < CT; ++ct)
        #pragma unroll
        for (int r = 0; r < 4; ++r)
            ep[w][(q * 4 + r) * EPS + ct * 16 + n16] = acc[ct][r];
    __syncthreads();
    const int lr = lane & 15;
    const int cc = (lane >> 4) * (BN / 4);
    int grow = rowBase + lr;
    if (grow < M) {
        float s = dinv_of(wsum[grow]);
        const float* src = &ep[w][lr * EPS + cc];
        #pragma unroll
        for (int u = 0; u < BN / 64; ++u) {
            int col0 = cc + u * 16;
            int slice = col0 >> 6, cw = col0 & 63;
            unsigned w0 = f32x4_to_fp8(src[u*16+ 0]*s, src[u*16+ 1]*s, src[u*16+ 2]*s, src[u*16+ 3]*s);
            unsigned w1 = f32x4_to_fp8(src[u*16+ 4]*s, src[u*16+ 5]*s, src[u*16+ 6]*s, src[u*16+ 7]*s);
            unsigned w2 = f32x4_to_fp8(src[u*16+ 8]*s, src[u*16+ 9]*s, src[u*16+10]*s, src[u*16+11]*s);
            unsigned w3 = f32x4_to_fp8(src[u*16+12]*s, src[u*16+13]*s, src[u*16+14]*s, src[u*16+15]*s);
            *(uint4*)&outf8[((size_t)slice * M + grow) * 64 + cw] = make_uint4(w0, w1, w2, w3);
        }
    }
}

// Fused layer1-gather + layer2-gemm. 512 thr, 16 nodes/block.
// Edge loop: 32 lanes/node (e=4 edge-lanes x cg=8 feature-groups, both slices).
// h rows -> LDS bf16 tile -> waves 0-3 do 16x64 MFMA GEMM vs wt2 -> fp8 out.
__global__ __launch_bounds__(512)
void g1g2_kernel(const unsigned char* __restrict__ xsb,      // xw1f8 [2][N][64]
                 const unsigned* __restrict__ slot,
                 const int* __restrict__ cnt, const int* __restrict__ wsum,
                 const float* __restrict__ b1, const unsigned short* __restrict__ wt2,
                 const int4* __restrict__ ovf, const int* __restrict__ ovfcnt,
                 unsigned char* __restrict__ xw2f8, int N) {
    constexpr int EPN = 4;
    __shared__ unsigned sbkt[16 * BSTR];
    __shared__ unsigned short hs[16 * KP];     // h tile, bf16
    __shared__ unsigned short wl[64 * KP];     // wt2
    __shared__ float ep[16 * 68];              // gemm epilogue
    const int t = threadIdx.x;
    const int node0 = blockIdx.x * 16;
    for (int i = t; i < 64 * KP / 8; i += 512)         // stage wt2 (17.4 KB)
        ((uint4*)wl)[i] = ((const uint4*)wt2)[i];
    for (int i = t; i < 16 * KP / 8; i += 512)         // zero h tile (tail rows)
        ((uint4*)hs)[i] = make_uint4(0, 0, 0, 0);
    if (t < 256) {                                     // stage buckets (cnt-gated)
        int ndl = t >> 4, part = t & 15;
        int snode = node0 + ndl; if (snode >= N) snode = N - 1;
        int sc = cnt[snode]; if (sc > CAP) sc = CAP;
        if (part * 4 < sc)
            *(uint4*)&sbkt[ndl * BSTR + part * 4] =
                *(const uint4*)&slot[(size_t)snode * CAP + part * 4];
    }
    __syncthreads();
    const int cg  = t & 7;           // feature group (16 feats); slice = cg>>2
    const int e   = (t >> 3) & 3;    // edge lane
    const int ndl = t >> 5;          // local node 0..15
    const int i = node0 + ndl;
    const bool iv = (i < N);
    const int ic = iv ? i : 0;
    const int cg3 = cg & 3;
    const size_t sb = (size_t)(cg >> 2) * N;
    const uint4* xs4 = (const uint4*)xsb;
    int mraw = iv ? cnt[ic] : 0;
    int m = mraw > CAP ? CAP : mraw;
    const unsigned* lb = &sbkt[ndl * BSTR];
    float acc[16] = {};
    int j = e;
    for (; j + EPN < m; j += 2 * EPN) {
        unsigned u0 = lb[j], u1 = lb[j + EPN];
        float c0 = (float)(u0 & 32767u), c1 = (float)(u1 & 32767u);
        uint4 a0 = xs4[(sb + (u0 >> 15)) * 4 + cg3];
        uint4 a1 = xs4[(sb + (u1 >> 15)) * 4 + cg3];
        float f0[16], f1[16];
        fp8x4_to_f32(a0.x, f0 + 0);  fp8x4_to_f32(a0.y, f0 + 4);
        fp8x4_to_f32(a0.z, f0 + 8);  fp8x4_to_f32(a0.w, f0 + 12);
        fp8x4_to_f32(a1.x, f1 + 0);  fp8x4_to_f32(a1.y, f1 + 4);
        fp8x4_to_f32(a1.z, f1 + 8);  fp8x4_to_f32(a1.w, f1 + 12);
        #pragma unroll
        for (int k = 0; k < 16; ++k) acc[k] += f0[k] * c0 + f1[k] * c1;
    }
    if (j < m) {
        unsigned u = lb[j];
        float c = (float)(u & 32767u);
        uint4 a = xs4[(sb + (u >> 15)) * 4 + cg3];
        float f[16];
        fp8x4_to_f32(a.x, f + 0);  fp8x4_to_f32(a.y, f + 4);
        fp8x4_to_f32(a.z, f + 8);  fp8x4_to_f32(a.w, f + 12);
        #pragma unroll
        for (int k = 0; k < 16; ++k) acc[k] += f[k] * c;
    }
    if (mraw > CAP) {                     // inline overflow (normally skipped)
        int oc = *ovfcnt; if (oc > OVFCAP) oc = OVFCAP;
        for (int k = e; k < oc; k += EPN) {
            int4 r4 = ovf[k];
            if (r4.y == i) {
                float c = (float)r4.z;
                uint4 a = xs4[(sb + r4.x) * 4 + cg3];
                float f[16];
                fp8x4_to_f32(a.x, f + 0);  fp8x4_to_f32(a.y, f + 4);
                fp8x4_to_f32(a.z, f + 8);  fp8x4_to_f32(a.w, f + 12);
                #pragma unroll
                for (int kk = 0; kk < 16; ++kk) acc[kk] += f[kk] * c;
            }
        }
    }
    #pragma unroll
    for (int k = 0; k < 16; ++k) {        // reduce over e (bits 3-4 of lane)
        acc[k] += __shfl_xor(acc[k], 8);
        acc[k] += __shfl_xor(acc[k], 16);
    }
    if (e == 0 && iv) {                   // finalize h[i][cg*16..+16] -> LDS bf16
        float d = dinv_of(wsum[i]);
        float sa = d * (1.0f / 32768.0f);
        uint4 sv = xs4[(sb + i) * 4 + cg3];
        float sf[16];
        fp8x4_to_f32(sv.x, sf + 0);  fp8x4_to_f32(sv.y, sf + 4);
        fp8x4_to_f32(sv.z, sf + 8);  fp8x4_to_f32(sv.w, sf + 12);
        const float* bb = &b1[cg * 16];
        float o[16];
        #pragma unroll
        for (int k = 0; k < 16; ++k)
            o[k] = fmaxf(acc[k] * sa + sf[k] * d + bb[k], 0.f);
        unsigned short* dst = &hs[ndl * KP + cg * 16];
        unsigned pw[8];
        #pragma unroll
        for (int k = 0; k < 8; ++k)
            pw[k] = (unsigned)f2bf(o[2 * k]) | ((unsigned)f2bf(o[2 * k + 1]) << 16);
        *(uint4*)&dst[0] = make_uint4(pw[0], pw[1], pw[2], pw[3]);
        *(uint4*)&dst[8] = make_uint4(pw[4], pw[5], pw[6], pw[7]);
    }
    __syncthreads();
    // GEMM: waves 0-3, wave w -> col tile w (16 cols), K=128
    const int w = t >> 6, lane = t & 63;
    if (w < 4) {
        const int n16 = lane & 15, q = lane >> 4;
        f32x4 a2 = (f32x4){0.f, 0.f, 0.f, 0.f};
        #pragma unroll
        for (int kt = 0; kt < 4; ++kt) {
            bf16x8 af = *(const bf16x8*)&hs[(lane & 15) * KP + kt * 32 + q * 8];
            bf16x8 bfr = *(const bf16x8*)&wl[(w * 16 + n16) * KP + kt * 32 + q * 8];
            a2 = __builtin_amdgcn_mfma_f32_16x16x32_bf16(af, bfr, a2, 0, 0, 0);
        }
        #pragma unroll
        for (int r = 0; r < 4; ++r)
            ep[(q * 4 + r) * 68 + w * 16 + n16] = a2[r];
    }
    __syncthreads();
    if (t < 64) {                         // pack fp8: lane -> (row, col chunk)
        int lr = t & 15, chunk = t >> 4;
        int grow = node0 + lr;
        if (grow < N) {
            float s = dinv_of(wsum[grow]);
            const float* src = &ep[lr * 68 + chunk * 16];
            unsigned w0 = f32x4_to_fp8(src[ 0]*s, src[ 1]*s, src[ 2]*s, src[ 3]*s);
            unsigned w1 = f32x4_to_fp8(src[ 4]*s, src[ 5]*s, src[ 6]*s, src[ 7]*s);
            unsigned w2 = f32x4_to_fp8(src[ 8]*s, src[ 9]*s, src[10]*s, src[11]*s);
            unsigned w3 = f32x4_to_fp8(src[12]*s, src[13]*s, src[14]*s, src[15]*s);
            *(uint4*)&xw2f8[(size_t)grow * 64 + chunk * 16] = make_uint4(w0, w1, w2, w3);
        }
    }
}

// Sliced fp8 aggregation with LDS-staged buckets (layer2 + fused mean-pool).
template <int F, int S, bool OB, bool POOL>
__global__ void gather_kernel(const unsigned char* __restrict__ xsb,
                              const unsigned* __restrict__ slot,
                              const int* __restrict__ cnt, const int* __restrict__ wsum,
                              const float* __restrict__ b, const int4* __restrict__ ovf,
                              const int* __restrict__ ovfcnt, void* __restrict__ outv, int N,
                              const int* __restrict__ gbatch, float* __restrict__ gsums,
                              float* __restrict__ gcnt) {
    constexpr int EPN = 4;           // edges in flight per node
    __shared__ unsigned sbkt[16 * BSTR];
    __shared__ float x1s[16 * 68];   // POOL only: per-node output tile
    __shared__ int gidl[16];         // POOL only: batch ids (-1 = invalid)
    const int slice = (S > 1) ? ((int)blockIdx.x % S) : 0;
    const int grp = (S > 1) ? ((int)blockIdx.x / S) : blockIdx.x;
    const int t = threadIdx.x;
    const int node0 = grp * 16;
    {   // stage buckets (coalesced), but only the live entries (< cnt)
        int ndl = t >> 4, part = t & 15;
        int snode = node0 + ndl; if (snode >= N) snode = N - 1;
        int sc = cnt[snode]; if (sc > CAP) sc = CAP;
        if (part * 4 < sc)
            *(uint4*)&sbkt[ndl * BSTR + part * 4] =
                *(const uint4*)&slot[(size_t)snode * CAP + part * 4];
    }
    if constexpr (POOL) {
        if (t < 16) {
            int sn = node0 + t;
            gidl[t] = (sn < N) ? gbatch[sn] : -1;
        }
    }
    __syncthreads();
    const int w = t >> 6, lane = t & 63;
    const int cg = lane & 3;
    const int e  = (lane >> 2) & 3;
    const int nd = lane >> 4;
    const int ndl = w * 4 + nd;          // local node 0..15
    const int i = node0 + ndl;
    const bool iv = (i < N);
    const int ic = iv ? i : 0;
    const uint4* xs4 = (const uint4*)(xsb + (size_t)slice * N * 64);
    int mraw = iv ? cnt[ic] : 0;
    int m = mraw > CAP ? CAP : mraw;
    const unsigned* lb = &sbkt[ndl * BSTR];
    float acc[16] = {};
    int j = e;
    for (; j + EPN < m; j += 2 * EPN) {
        unsigned u0 = lb[j], u1 = lb[j + EPN];
        float c0 = (float)(u0 & 32767u), c1 = (float)(u1 & 32767u);
        uint4 a0 = xs4[(size_t)(u0 >> 15) * 4 + cg];
        uint4 a1 = xs4[(size_t)(u1 >> 15) * 4 + cg];
        float f0[16], f1[16];
        fp8x4_to_f32(a0.x, f0 + 0);  fp8x4_to_f32(a0.y, f0 + 4);
        fp8x4_to_f32(a0.z, f0 + 8);  fp8x4_to_f32(a0.w, f0 + 12);
        fp8x4_to_f32(a1.x, f1 + 0);  fp8x4_to_f32(a1.y, f1 + 4);
        fp8x4_to_f32(a1.z, f1 + 8);  fp8x4_to_f32(a1.w, f1 + 12);
        #pragma unroll
        for (int k = 0; k < 16; ++k) acc[k] += f0[k] * c0 + f1[k] * c1;
    }
    if (j < m) {
        unsigned u = lb[j];
        float c = (float)(u & 32767u);
        uint4 a = xs4[(size_t)(u >> 15) * 4 + cg];
        float f[16];
        fp8x4_to_f32(a.x, f + 0);  fp8x4_to_f32(a.y, f + 4);
        fp8x4_to_f32(a.z, f + 8);  fp8x4_to_f32(a.w, f + 12);
        #pragma unroll
        for (int k = 0; k < 16; ++k) acc[k] += f[k] * c;
    }
    if (mraw > CAP) {                     // inline overflow (normally skipped)
        int oc = *ovfcnt; if (oc > OVFCAP) oc = OVFCAP;
        for (int k = e; k < oc; k += EPN) {
            int4 r4 = ovf[k];
            if (r4.y == i) {
                float c = (float)r4.z;
                uint4 a = xs4[(size_t)r4.x * 4 + cg];
                float f[16];
                fp8x4_to_f32(a.x, f + 0);  fp8x4_to_f32(a.y, f + 4);
                fp8x4_to_f32(a.z, f + 8);  fp8x4_to_f32(a.w, f + 12);
                #pragma unroll
                for (int kk = 0; kk < 16; ++kk) acc[kk] += f[kk] * c;
            }
        }
    }
    #pragma unroll
    for (int k = 0; k < 16; ++k) {
        acc[k] += __shfl_xor(acc[k], 4);
        acc[k] += __shfl_xor(acc[k], 8);
    }
    if (e == 0 && iv) {
        float d = dinv_of(wsum[i]);
        float sa = d * (1.0f / 32768.0f);
        uint4 sv = xs4[(size_t)i * 4 + cg];
        float sf[16];
        fp8x4_to_f32(sv.x, sf + 0);  fp8x4_to_f32(sv.y, sf + 4);
        fp8x4_to_f32(sv.z, sf + 8);  fp8x4_to_f32(sv.w, sf + 12);
        const float* bb = &b[slice * 64 + cg * 16];
        float o[16];
        #pragma unroll
        for (int k = 0; k < 16; ++k)
            o[k] = fmaxf(acc[k] * sa + sf[k] * d + bb[k], 0.f);
        if (OB) {
            unsigned short* dst = (unsigned short*)outv + (size_t)i * F + slice * 64 + cg * 16;
            unsigned pw[8];
            #pragma unroll
            for (int k = 0; k < 8; ++k)
                pw[k] = (unsigned)f2bf(o[2 * k]) | ((unsigned)f2bf(o[2 * k + 1]) << 16);
            *(uint4*)&dst[0] = make_uint4(pw[0], pw[1], pw[2], pw[3]);
            *(uint4*)&dst[8] = make_uint4(pw[4], pw[5], pw[6], pw[7]);
        } else if constexpr (!POOL) {
            float* dst = (float*)outv + (size_t)i * F + slice * 64 + cg * 16;
            *(float4*)&dst[0]  = make_float4(o[0], o[1], o[2], o[3]);
            *(float4*)&dst[4]  = make_float4(o[4], o[5], o[6], o[7]);
            *(float4*)&dst[8]  = make_float4(o[8], o[9], o[10], o[11]);
            *(float4*)&dst[12] = make_float4(o[12], o[13], o[14], o[15]);
        } else {
            float* dst = &x1s[ndl * 68 + cg * 16];
            *(float4*)&dst[0]  = make_float4(o[0], o[1], o[2], o[3]);
            *(float4*)&dst[4]  = make_float4(o[4], o[5], o[6], o[7]);
            *(float4*)&dst[8]  = make_float4(o[8], o[9], o[10], o[11]);
            *(float4*)&dst[12] = make_float4(o[12], o[13], o[14], o[15]);
        }
    }
    if constexpr (POOL) {
        __syncthreads();
        if (t < 64) {                    // feature f = t: run-reduce the 16 nodes
            const int f = t;
            float run = 0.f; int gcur = -1;
            #pragma unroll 4
            for (int n = 0; n < 16; ++n) {
                int g = gidl[n];
                if (g < 0) break;        // sorted: invalid only at the tail
                if (g != gcur) {
                    if (gcur >= 0) atomicAdd(&gsums[gcur * 64 + f], run);
                    run = 0.f; gcur = g;
                }
                run += x1s[n * 68 + f];
            }
            if (gcur >= 0) atomicAdd(&gsums[gcur * 64 + f], run);
        } else if (t == 64) {            // node counts per graph
            float rc = 0.f; int gcur = -1;
            for (int n = 0; n < 16; ++n) {
                int g = gidl[n];
                if (g < 0) break;
                if (g != gcur) {
                    if (gcur >= 0) atomicAdd(&gcnt[gcur], rc);
                    rc = 0.f; gcur = g;
                }
                rc += 1.f;
            }
            if (gcur >= 0) atomicAdd(&gcnt[gcur], rc);
        }
    }
}

// Head: one block per graph.
__global__ void head_kernel(const float* __restrict__ sums, const float* __restrict__ cnt,
                            const float* __restrict__ fc1W, const float* __restrict__ fc1b,
                            const float* __restrict__ fc2W, const float* __restrict__ fc2b,
                            float* __restrict__ out) {
    __shared__ float x2s[64];
    __shared__ float hs[128];
    __shared__ float lg[2];
    const int g = blockIdx.x;
    const int t = threadIdx.x;
    if (t < 64) {
        float c = fmaxf(cnt[g], 1.f);
        x2s[t] = sums[g * 64 + t] / c;
    }
    __syncthreads();
    {
        float a = fc1b[t];
        #pragma unroll 8
        for (int j = 0; j < 64; ++j) a += x2s[j] * fc1W[j * 128 + t];
        hs[t] = fmaxf(a, 0.f);
    }
    __syncthreads();
    {
        int m = t >> 6, l = t & 63;
        float p = hs[l] * fc2W[l * 2 + m] + hs[l + 64] * fc2W[(l + 64) * 2 + m];
        #pragma unroll
        for (int off = 1; off < 64; off <<= 1) p += __shfl_xor(p, off);
        if (l == 0) lg[m] = p + fc2b[m];
    }
    __syncthreads();
    if (t == 0) {
        float l0 = lg[0], l1 = lg[1];
        float mx = fmaxf(l0, l1);
        float lse = mx + logf(expf(l0 - mx) + expf(l1 - mx));
        out[g * 2 + 0] = l0 - lse;
        out[g * 2 + 1] = l1 - lse;
    }
}

extern "C" void kernel_launch(void* const* d_in, const int* in_sizes, int n_in,
                              void* d_out, int out_size, void* d_ws, size_t ws_size,
                              hipStream_t stream) {
    const float* x      = (const float*)d_in[0];
    const int*   eidx   = (const int*)d_in[1];
    const float* ew     = (const float*)d_in[2];
    const int*   batch  = (const int*)d_in[3];
    const float* W1     = (const float*)d_in[4];
    const float* b1     = (const float*)d_in[5];
    const float* W2     = (const float*)d_in[6];
    const float* b2     = (const float*)d_in[7];
    const float* fc1W   = (const float*)d_in[8];
    const float* fc1b   = (const float*)d_in[9];
    const float* fc2W   = (const float*)d_in[10];
    const float* fc2b   = (const float*)d_in[11];
    float* out = (float*)d_out;

    const int N = in_sizes[3];          // 50000 nodes
    const int E = in_sizes[2];          // 1600000 edges
    const int G = 64;
    const int* rows = eidx;
    const int* cols = eidx + E;
    const int NR = (N + NRANGE - 1) / NRANGE;
    const int RSEG = E / NRANGE + 2048;

    float* ws = (float*)d_ws;
    size_t off = 0;
    auto alloc = [&](size_t n) { float* p = ws + off; off += (n + 15) & ~(size_t)15; return p; };
    // --- zero-initialized region ---
    float*    sums     = alloc(64 * 64);
    float*    cntf     = alloc(16);
    int*      ovfcnt   = (int*)alloc(16);
    int*      rangeCnt = (int*)alloc(NRANGE);
    int*      cnt      = (int*)alloc(N);          // degree (exact)
    int*      wsum     = (int*)alloc(N);          // q15 weight sum -> dinv
    size_t zfloats = off;
    // --- rest ---
    unsigned short* wt1 = (unsigned short*)alloc(128 * KP / 2 + 16);
    unsigned short* wt2 = (unsigned short*)alloc(64 * KP / 2 + 16);
    unsigned* slot   = (unsigned*)alloc((size_t)N * CAP);
    int4*     ovf    = (int4*)alloc((size_t)OVFCAP * 4);
    float*    bufA   = alloc((size_t)N * 128);   // xw1f8 | xw2f8 (disjoint)
    float*    bufB   = alloc((size_t)N * 128);   // rng
    unsigned char*  xw1f8 = (unsigned char*)bufA;                        // [2][N][64] fp8
    unsigned char*  xw2f8 = (unsigned char*)bufA + (size_t)2 * N * 64;   // [1][N][64] fp8
    uint2*          rng   = (uint2*)bufB;                                // NRANGE*RSEG uint2
    (void)ws_size;

    hipMemsetAsync(d_ws, 0, zfloats * sizeof(float), stream);

    // CSR build (+ weight prep riding as 2 extra blocks on part)
    const bool fits = (NR <= MAXNRP) &&
                      ((size_t)NRANGE * RSEG * sizeof(uint2) <= (size_t)N * 512);
    if (fits) {
        part_kernel<<<PARTNB + 2, 512, 0, stream>>>(rows, cols, ew, rangeCnt, rng, E, NR, RSEG,
                                                    W1, W2, wt1, wt2);
        place_kernel<<<NRANGE, 512, 0, stream>>>(rng, rangeCnt, cnt, wsum, slot, ovf, ovfcnt,
                                                 NR, RSEG, N);
    } else {
        part_kernel<<<PARTNB + 2, 512, 0, stream>>>(rows, cols, ew, rangeCnt, rng, 0, NR, RSEG,
                                                    W1, W2, wt1, wt2);   // weights still prepped
        place_simple_kernel<<<(E + 255) / 256, 256, 0, stream>>>(rows, cols, ew, cnt, wsum,
                                                                 slot, ovf, ovfcnt, E);
    }

    // Layer 1 GEMM: MFMA (fp32 A) -> fp8 table (2 slices)
    gemm_mfma_kernel<128, true><<<(N + 63) / 64, 256, 0, stream>>>(x, wt1, wsum, xw1f8, N);

    // Fused: layer1 gather (both slices) + layer2 GEMM -> xw2f8
    g1g2_kernel<<<(N + 15) / 16, 512, 0, stream>>>(xw1f8, slot, cnt, wsum, b1, wt2,
                                                   ovf, ovfcnt, xw2f8, N);

    // Layer 2 gather + fused mean-pool accumulation (x1 never materialized)
    gather_kernel<64, 1, false, true><<<(N + 15) / 16, 256, 0, stream>>>(
        xw2f8, slot, cnt, wsum, b2, ovf, ovfcnt, nullptr, N, batch, sums, cntf);

    head_kernel<<<G, 128, 0, stream>>>(sums, cntf, fc1W, fc1b, fc2W, fc2b, out);
}

// Round 7
// 210.873 us; speedup vs baseline: 1.0281x; 1.0281x over previous
//
#include <hip/hip_runtime.h>
#include <hip/hip_bf16.h>

// ---------------------------------------------------------------------------
// GCN: h = relu(GCNConv(x,W1,b1)); x1 = relu(GCNConv(h,W2,b2));
//      x2 = meanpool(x1,batch); out = log_softmax(relu(x2@fc1+b)@fc2+b)
//
// R20: R19's g1g2 fusion reverted (was +3us: random-gather latency dominates,
// not hbf bytes). Back to R18 structure + SLICE-MAJOR gather grid:
//  - gather1's old slice=blockIdx%2 kept both 3.2MB fp8 slices live in every
//    XCD L2 (6.4MB > 4MB -> 43% miss, 88MB FETCH). Now slice=blockIdx/ngrp:
//    slice-0 blocks dispatch (and mostly complete) first, so the active
//    slice fits per-XCD L2 -> random gathers become L2 hits.
//  - Keeps: R18 staged part (write-combined rng flush), exclusive-range
//    place with LDS cursors, inline dinv from wsum, fused pool in gather2,
//    cnt-gated slot staging, weight-prep rider on part.
// ---------------------------------------------------------------------------

#define CAP 64
#define OVFCAP 8192
#define NRANGE 512   // exclusive ranges; == part scan width (threads/block)
#define MAXNRP 2048  // max nodes per range (LDS cursor arrays in place)
#define BSTR 68      // LDS bucket stride (words)
#define KP 136       // bf16 weight row stride (128 + 8 pad)
#define PARTNB 256   // edge-partition blocks (weight blocks follow)
#define PBUF 6400    // staged records per part block (>= ceil(E/PARTNB))

typedef float v2f  __attribute__((ext_vector_type(2)));
typedef float f32x4 __attribute__((ext_vector_type(4)));
typedef short bf16x8 __attribute__((ext_vector_type(8)));

__device__ inline unsigned short f2bf(float f) {   // fp32 -> bf16 RNE
    unsigned u = __float_as_uint(f);
    u += 0x7FFFu + ((u >> 16) & 1u);
    return (unsigned short)(u >> 16);
}
__device__ inline void fp8x4_to_f32(unsigned w, float* o) {
    v2f lo = __builtin_amdgcn_cvt_pk_f32_fp8((int)w, false);
    v2f hi = __builtin_amdgcn_cvt_pk_f32_fp8((int)w, true);
    o[0] = lo[0]; o[1] = lo[1]; o[2] = hi[0]; o[3] = hi[1];
}
__device__ inline unsigned f32x4_to_fp8(float a, float b, float c, float d) {
    int w = 0;
    w = __builtin_amdgcn_cvt_pk_fp8_f32(a, b, w, false);
    w = __builtin_amdgcn_cvt_pk_fp8_f32(c, d, w, true);
    return (unsigned)w;
}
__device__ inline float dinv_of(int ws) {          // deg^{-1/2} incl. self-loop
    return rsqrtf((float)ws * (1.0f / 32768.0f) + 1.0f);
}

// P1: partition edges into NRANGE per-range lists rng[r] of (col, row<<15|q15(ew)).
// In-LDS staged + coalesced flush. Blocks >= PARTNB do the weight transpose.
__global__ __launch_bounds__(512)
void part_kernel(const int* __restrict__ rows, const int* __restrict__ cols,
                 const float* __restrict__ ew, int* __restrict__ rangeCnt,
                 uint2* __restrict__ rng, int E, int NR, int RSEG,
                 const float* __restrict__ W1, const float* __restrict__ W2,
                 unsigned short* __restrict__ wt1, unsigned short* __restrict__ wt2) {
    const int t = threadIdx.x;
    if (blockIdx.x >= PARTNB) {               // weight prep: wt[c][k] = W[k][c] (bf16)
        if (blockIdx.x == PARTNB) {
            for (int i = t; i < 128 * 128; i += 512) {
                int c = i >> 7, k = i & 127;
                wt1[c * KP + k] = f2bf(W1[k * 128 + c]);
            }
        } else {
            for (int i = t; i < 64 * 128; i += 512) {
                int c = i >> 7, k = i & 127;
                wt2[c * KP + k] = f2bf(W2[k * 64 + c]);
            }
        }
        return;
    }
    __shared__ uint2 buf[PBUF];      // range-sorted staging (51.2 KB)
    __shared__ int hcnt[NRANGE];     // histogram, then scatter cursor
    __shared__ int lbase[NRANGE];    // local exclusive base
    __shared__ int gbase[NRANGE];    // reserved global base
    __shared__ int wtot[8];
    const int CS = (E + PARTNB - 1) / PARTNB;
    const int e0 = blockIdx.x * CS, e1 = min(e0 + CS, E);
    const int M = e1 - e0;

    if (CS <= PBUF) {
        // ---- staged path ----
        for (int i = t; i < NRANGE; i += 512) hcnt[i] = 0;
        __syncthreads();
        for (int e = e0 + t; e < e1; e += 512)
            atomicAdd(&hcnt[cols[e] / NR], 1);
        __syncthreads();
        {   // block-wide exclusive scan over the 512 range counts (1/thread)
            int v = hcnt[t];
            int inc = v;
            #pragma unroll
            for (int off = 1; off < 64; off <<= 1) {
                int n = __shfl_up(inc, off);
                if ((t & 63) >= off) inc += n;
            }
            const int w = t >> 6;
            if ((t & 63) == 63) wtot[w] = inc;
            __syncthreads();
            int wo = 0;
            for (int k = 0; k < w; ++k) wo += wtot[k];
            int excl = wo + inc - v;
            lbase[t] = excl;
            gbase[t] = (v > 0) ? atomicAdd(&rangeCnt[t], v) : 0;
            hcnt[t] = excl;              // becomes scatter cursor
        }
        __syncthreads();
        for (int e = e0 + t; e < e1; e += 512) {   // scatter into LDS by range
            int c = cols[e];
            int r = c / NR;
            int q = (int)(ew[e] * 32768.0f);
            if (q > 32767) q = 32767;
            unsigned rec = ((unsigned)rows[e] << 15) | (unsigned)q;
            int p = atomicAdd(&hcnt[r], 1);
            buf[p] = make_uint2((unsigned)c, rec);
        }
        __syncthreads();
        for (int i = t; i < M; i += 512) {         // coalesced flush
            uint2 u = buf[i];
            int r = (int)u.x / NR;
            int idx = gbase[r] + (i - lbase[r]);
            if (idx < RSEG) rng[(size_t)r * RSEG + idx] = u;
        }
    } else {
        // ---- fallback: direct scatter (R16 path) ----
        for (int i = t; i < NRANGE; i += 512) hcnt[i] = 0;
        __syncthreads();
        for (int e = e0 + t; e < e1; e += 512)
            atomicAdd(&hcnt[cols[e] / NR], 1);
        __syncthreads();
        for (int i = t; i < NRANGE; i += 512)
            hcnt[i] = atomicAdd(&rangeCnt[i], hcnt[i]);
        __syncthreads();
        for (int e = e0 + t; e < e1; e += 512) {
            int c = cols[e];
            int r = c / NR;
            int q = (int)(ew[e] * 32768.0f);
            if (q > 32767) q = 32767;
            unsigned rec = ((unsigned)rows[e] << 15) | (unsigned)q;
            int pos = atomicAdd(&hcnt[r], 1);
            if (pos < RSEG) rng[(size_t)r * RSEG + pos] = make_uint2((unsigned)c, rec);
        }
    }
}

// P2: block r exclusively owns range r -> LDS position cursors from 0.
// cnt/wsum are exact (deterministic) side products; no histogram/scan needed.
__global__ __launch_bounds__(512)
void place_kernel(const uint2* __restrict__ rng, const int* __restrict__ rangeCnt,
                  int* __restrict__ cnt, int* __restrict__ wsum,
                  unsigned* __restrict__ slot, int4* __restrict__ ovf,
                  int* __restrict__ ovfcnt, int NR, int RSEG, int N) {
    __shared__ int cur[MAXNRP];
    __shared__ int wsl[MAXNRP];
    const int r = blockIdx.x;
    const int t = threadIdx.x;
    const int n0 = r * NR;
    for (int n = t; n < NR; n += 512) { cur[n] = 0; wsl[n] = 0; }
    __syncthreads();
    const int M = min(rangeCnt[r], RSEG);
    const uint2* lst = rng + (size_t)r * RSEG;
    for (int k = t; k < M; k += 512) {
        uint2 u2 = lst[k];
        int cl = (int)u2.x - n0;
        int q = (int)(u2.y & 32767u);
        int pos = atomicAdd(&cur[cl], 1);
        atomicAdd(&wsl[cl], q);
        if (pos < CAP) {
            slot[(size_t)u2.x * CAP + pos] = u2.y;
        } else {
            int o = atomicAdd(ovfcnt, 1);
            if (o < OVFCAP)
                ovf[o] = make_int4((int)(u2.y >> 15), (int)u2.x, q, 0);
        }
    }
    __syncthreads();
    for (int n = t; n < NR; n += 512) {
        int gn = n0 + n;
        if (gn < N) { cnt[gn] = cur[n]; wsum[gn] = wsl[n]; }
    }
}

// Fallback for shapes the range partition can't handle (not taken here).
__global__ void place_simple_kernel(const int* __restrict__ rows, const int* __restrict__ cols,
                                    const float* __restrict__ ew, int* __restrict__ cnt,
                                    int* __restrict__ wsum,
                                    unsigned* __restrict__ slot, int4* __restrict__ ovf,
                                    int* __restrict__ ovfcnt, int E) {
    int e = blockIdx.x * 256 + threadIdx.x;
    if (e >= E) return;
    int r = rows[e], c = cols[e];
    int q = (int)(ew[e] * 32768.0f);
    if (q > 32767) q = 32767;
    int pos = atomicAdd(&cnt[c], 1);
    atomicAdd(&wsum[c], q);
    if (pos < CAP) {
        slot[(size_t)c * CAP + pos] = ((unsigned)r << 15) | (unsigned)q;
    } else {
        int o = atomicAdd(ovfcnt, 1);
        if (o < OVFCAP) ovf[o] = make_int4(r, c, q, 0);
    }
}

// MFMA bf16 GEMM -> fp8 sliced table. outf8[slice][M][64] = (A@W)*dinv[row].
template <int BN, bool AF32>
__global__ __launch_bounds__(256)
void gemm_mfma_kernel(const void* __restrict__ Av, const unsigned short* __restrict__ wt,
                      const int* __restrict__ wsum, unsigned char* __restrict__ outf8,
                      int M) {
    constexpr int CT = BN / 16;          // col tiles
    constexpr int EPS = BN + 4;          // epilogue LDS row stride (floats)
    __shared__ unsigned short wl[BN * KP];
    __shared__ float ep[4][16 * EPS];
    const int t = threadIdx.x;
    for (int i = t; i < BN * KP / 8; i += 256)
        ((uint4*)wl)[i] = ((const uint4*)wt)[i];
    __syncthreads();
    const int w = t >> 6, lane = t & 63;
    const int n16 = lane & 15, q = lane >> 4;
    const int rowBase = blockIdx.x * 64 + w * 16;
    int arow = rowBase + n16; if (arow >= M) arow = M - 1;
    f32x4 acc[CT];
    #pragma unroll
    for (int ct = 0; ct < CT; ++ct) acc[ct] = (f32x4){0.f, 0.f, 0.f, 0.f};
    #pragma unroll
    for (int kt = 0; kt < 4; ++kt) {
        bf16x8 af;
        if (AF32) {
            const float* ap = (const float*)Av + (size_t)arow * 128 + kt * 32 + q * 8;
            float4 a0 = *(const float4*)ap;
            float4 a1 = *(const float4*)(ap + 4);
            af[0] = (short)f2bf(a0.x); af[1] = (short)f2bf(a0.y);
            af[2] = (short)f2bf(a0.z); af[3] = (short)f2bf(a0.w);
            af[4] = (short)f2bf(a1.x); af[5] = (short)f2bf(a1.y);
            af[6] = (short)f2bf(a1.z); af[7] = (short)f2bf(a1.w);
        } else {
            af = *(const bf16x8*)((const unsigned short*)Av + (size_t)arow * 128 + kt * 32 + q * 8);
        }
        #pragma unroll
        for (int ct = 0; ct < CT; ++ct) {
            bf16x8 bfr = *(const bf16x8*)&wl[(ct * 16 + n16) * KP + kt * 32 + q * 8];
            acc[ct] = __builtin_amdgcn_mfma_f32_16x16x32_bf16(af, bfr, acc[ct], 0, 0, 0);
        }
    }
    #pragma unroll
    for (int ct = 0; ct < CT; ++ct)
        #pragma unroll
        for (int r = 0; r < 4; ++r)
            ep[w][(q * 4 + r) * EPS + ct * 16 + n16] = acc[ct][r];
    __syncthreads();
    const int lr = lane & 15;
    const int cc = (lane >> 4) * (BN / 4);
    int grow = rowBase + lr;
    if (grow < M) {
        float s = dinv_of(wsum[grow]);
        const float* src = &ep[w][lr * EPS + cc];
        #pragma unroll
        for (int u = 0; u < BN / 64; ++u) {
            int col0 = cc + u * 16;
            int slice = col0 >> 6, cw = col0 & 63;
            unsigned w0 = f32x4_to_fp8(src[u*16+ 0]*s, src[u*16+ 1]*s, src[u*16+ 2]*s, src[u*16+ 3]*s);
            unsigned w1 = f32x4_to_fp8(src[u*16+ 4]*s, src[u*16+ 5]*s, src[u*16+ 6]*s, src[u*16+ 7]*s);
            unsigned w2 = f32x4_to_fp8(src[u*16+ 8]*s, src[u*16+ 9]*s, src[u*16+10]*s, src[u*16+11]*s);
            unsigned w3 = f32x4_to_fp8(src[u*16+12]*s, src[u*16+13]*s, src[u*16+14]*s, src[u*16+15]*s);
            *(uint4*)&outf8[((size_t)slice * M + grow) * 64 + cw] = make_uint4(w0, w1, w2, w3);
        }
    }
}

// Sliced fp8 aggregation with LDS-staged buckets.
// SLICE-MAJOR grid: slice = blockIdx / ngrp so one 3.2MB slice is the active
// L2 working set at a time (was %S interleave -> 6.4MB thrash, 43% miss).
// OB: output bf16 (layer1 h). POOL: fused mean-pool accumulation (layer2).
template <int F, int S, bool OB, bool POOL>
__global__ void gather_kernel(const unsigned char* __restrict__ xsb,
                              const unsigned* __restrict__ slot,
                              const int* __restrict__ cnt, const int* __restrict__ wsum,
                              const float* __restrict__ b, const int4* __restrict__ ovf,
                              const int* __restrict__ ovfcnt, void* __restrict__ outv, int N,
                              const int* __restrict__ gbatch, float* __restrict__ gsums,
                              float* __restrict__ gcnt) {
    constexpr int EPN = 4;           // edges in flight per node
    __shared__ unsigned sbkt[16 * BSTR];
    __shared__ float x1s[16 * 68];   // POOL only: per-node output tile
    __shared__ int gidl[16];         // POOL only: batch ids (-1 = invalid)
    const int ngrp = (S > 1) ? ((int)gridDim.x / S) : (int)gridDim.x;
    const int slice = (S > 1) ? ((int)blockIdx.x / ngrp) : 0;
    const int grp = (S > 1) ? ((int)blockIdx.x % ngrp) : blockIdx.x;
    const int t = threadIdx.x;
    const int node0 = grp * 16;
    {   // stage buckets (coalesced), but only the live entries (< cnt)
        int ndl = t >> 4, part = t & 15;
        int snode = node0 + ndl; if (snode >= N) snode = N - 1;
        int sc = cnt[snode]; if (sc > CAP) sc = CAP;
        if (part * 4 < sc)
            *(uint4*)&sbkt[ndl * BSTR + part * 4] =
                *(const uint4*)&slot[(size_t)snode * CAP + part * 4];
    }
    if constexpr (POOL) {
        if (t < 16) {
            int sn = node0 + t;
            gidl[t] = (sn < N) ? gbatch[sn] : -1;
        }
    }
    __syncthreads();
    const int w = t >> 6, lane = t & 63;
    const int cg = lane & 3;
    const int e  = (lane >> 2) & 3;
    const int nd = lane >> 4;
    const int ndl = w * 4 + nd;          // local node 0..15
    const int i = node0 + ndl;
    const bool iv = (i < N);
    const int ic = iv ? i : 0;
    const uint4* xs4 = (const uint4*)(xsb + (size_t)slice * N * 64);
    int mraw = iv ? cnt[ic] : 0;
    int m = mraw > CAP ? CAP : mraw;
    const unsigned* lb = &sbkt[ndl * BSTR];
    float acc[16] = {};
    int j = e;
    for (; j + EPN < m; j += 2 * EPN) {
        unsigned u0 = lb[j], u1 = lb[j + EPN];
        float c0 = (float)(u0 & 32767u), c1 = (float)(u1 & 32767u);
        uint4 a0 = xs4[(size_t)(u0 >> 15) * 4 + cg];
        uint4 a1 = xs4[(size_t)(u1 >> 15) * 4 + cg];
        float f0[16], f1[16];
        fp8x4_to_f32(a0.x, f0 + 0);  fp8x4_to_f32(a0.y, f0 + 4);
        fp8x4_to_f32(a0.z, f0 + 8);  fp8x4_to_f32(a0.w, f0 + 12);
        fp8x4_to_f32(a1.x, f1 + 0);  fp8x4_to_f32(a1.y, f1 + 4);
        fp8x4_to_f32(a1.z, f1 + 8);  fp8x4_to_f32(a1.w, f1 + 12);
        #pragma unroll
        for (int k = 0; k < 16; ++k) acc[k] += f0[k] * c0 + f1[k] * c1;
    }
    if (j < m) {
        unsigned u = lb[j];
        float c = (float)(u & 32767u);
        uint4 a = xs4[(size_t)(u >> 15) * 4 + cg];
        float f[16];
        fp8x4_to_f32(a.x, f + 0);  fp8x4_to_f32(a.y, f + 4);
        fp8x4_to_f32(a.z, f + 8);  fp8x4_to_f32(a.w, f + 12);
        #pragma unroll
        for (int k = 0; k < 16; ++k) acc[k] += f[k] * c;
    }
    if (mraw > CAP) {                     // inline overflow (normally skipped)
        int oc = *ovfcnt; if (oc > OVFCAP) oc = OVFCAP;
        for (int k = e; k < oc; k += EPN) {
            int4 r4 = ovf[k];
            if (r4.y == i) {
                float c = (float)r4.z;
                uint4 a = xs4[(size_t)r4.x * 4 + cg];
                float f[16];
                fp8x4_to_f32(a.x, f + 0);  fp8x4_to_f32(a.y, f + 4);
                fp8x4_to_f32(a.z, f + 8);  fp8x4_to_f32(a.w, f + 12);
                #pragma unroll
                for (int kk = 0; kk < 16; ++kk) acc[kk] += f[kk] * c;
            }
        }
    }
    #pragma unroll
    for (int k = 0; k < 16; ++k) {
        acc[k] += __shfl_xor(acc[k], 4);
        acc[k] += __shfl_xor(acc[k], 8);
    }
    if (e == 0 && iv) {
        float d = dinv_of(wsum[i]);
        float sa = d * (1.0f / 32768.0f);
        uint4 sv = xs4[(size_t)i * 4 + cg];
        float sf[16];
        fp8x4_to_f32(sv.x, sf + 0);  fp8x4_to_f32(sv.y, sf + 4);
        fp8x4_to_f32(sv.z, sf + 8);  fp8x4_to_f32(sv.w, sf + 12);
        const float* bb = &b[slice * 64 + cg * 16];
        float o[16];
        #pragma unroll
        for (int k = 0; k < 16; ++k)
            o[k] = fmaxf(acc[k] * sa + sf[k] * d + bb[k], 0.f);
        if (OB) {
            unsigned short* dst = (unsigned short*)outv + (size_t)i * F + slice * 64 + cg * 16;
            unsigned pw[8];
            #pragma unroll
            for (int k = 0; k < 8; ++k)
                pw[k] = (unsigned)f2bf(o[2 * k]) | ((unsigned)f2bf(o[2 * k + 1]) << 16);
            *(uint4*)&dst[0] = make_uint4(pw[0], pw[1], pw[2], pw[3]);
            *(uint4*)&dst[8] = make_uint4(pw[4], pw[5], pw[6], pw[7]);
        } else if constexpr (!POOL) {
            float* dst = (float*)outv + (size_t)i * F + slice * 64 + cg * 16;
            *(float4*)&dst[0]  = make_float4(o[0], o[1], o[2], o[3]);
            *(float4*)&dst[4]  = make_float4(o[4], o[5], o[6], o[7]);
            *(float4*)&dst[8]  = make_float4(o[8], o[9], o[10], o[11]);
            *(float4*)&dst[12] = make_float4(o[12], o[13], o[14], o[15]);
        } else {
            float* dst = &x1s[ndl * 68 + cg * 16];
            *(float4*)&dst[0]  = make_float4(o[0], o[1], o[2], o[3]);
            *(float4*)&dst[4]  = make_float4(o[4], o[5], o[6], o[7]);
            *(float4*)&dst[8]  = make_float4(o[8], o[9], o[10], o[11]);
            *(float4*)&dst[12] = make_float4(o[12], o[13], o[14], o[15]);
        }
    }
    if constexpr (POOL) {
        __syncthreads();
        if (t < 64) {                    // feature f = t: run-reduce the 16 nodes
            const int f = t;
            float run = 0.f; int gcur = -1;
            #pragma unroll 4
            for (int n = 0; n < 16; ++n) {
                int g = gidl[n];
                if (g < 0) break;        // sorted: invalid only at the tail
                if (g != gcur) {
                    if (gcur >= 0) atomicAdd(&gsums[gcur * 64 + f], run);
                    run = 0.f; gcur = g;
                }
                run += x1s[n * 68 + f];
            }
            if (gcur >= 0) atomicAdd(&gsums[gcur * 64 + f], run);
        } else if (t == 64) {            // node counts per graph
            float rc = 0.f; int gcur = -1;
            for (int n = 0; n < 16; ++n) {
                int g = gidl[n];
                if (g < 0) break;
                if (g != gcur) {
                    if (gcur >= 0) atomicAdd(&gcnt[gcur], rc);
                    rc = 0.f; gcur = g;
                }
                rc += 1.f;
            }
            if (gcur >= 0) atomicAdd(&gcnt[gcur], rc);
        }
    }
}

// Head: one block per graph.
__global__ void head_kernel(const float* __restrict__ sums, const float* __restrict__ cnt,
                            const float* __restrict__ fc1W, const float* __restrict__ fc1b,
                            const float* __restrict__ fc2W, const float* __restrict__ fc2b,
                            float* __restrict__ out) {
    __shared__ float x2s[64];
    __shared__ float hs[128];
    __shared__ float lg[2];
    const int g = blockIdx.x;
    const int t = threadIdx.x;
    if (t < 64) {
        float c = fmaxf(cnt[g], 1.f);
        x2s[t] = sums[g * 64 + t] / c;
    }
    __syncthreads();
    {
        float a = fc1b[t];
        #pragma unroll 8
        for (int j = 0; j < 64; ++j) a += x2s[j] * fc1W[j * 128 + t];
        hs[t] = fmaxf(a, 0.f);
    }
    __syncthreads();
    {
        int m = t >> 6, l = t & 63;
        float p = hs[l] * fc2W[l * 2 + m] + hs[l + 64] * fc2W[(l + 64) * 2 + m];
        #pragma unroll
        for (int off = 1; off < 64; off <<= 1) p += __shfl_xor(p, off);
        if (l == 0) lg[m] = p + fc2b[m];
    }
    __syncthreads();
    if (t == 0) {
        float l0 = lg[0], l1 = lg[1];
        float mx = fmaxf(l0, l1);
        float lse = mx + logf(expf(l0 - mx) + expf(l1 - mx));
        out[g * 2 + 0] = l0 - lse;
        out[g * 2 + 1] = l1 - lse;
    }
}

extern "C" void kernel_launch(void* const* d_in, const int* in_sizes, int n_in,
                              void* d_out, int out_size, void* d_ws, size_t ws_size,
                              hipStream_t stream) {
    const float* x      = (const float*)d_in[0];
    const int*   eidx   = (const int*)d_in[1];
    const float* ew     = (const float*)d_in[2];
    const int*   batch  = (const int*)d_in[3];
    const float* W1     = (const float*)d_in[4];
    const float* b1     = (const float*)d_in[5];
    const float* W2     = (const float*)d_in[6];
    const float* b2     = (const float*)d_in[7];
    const float* fc1W   = (const float*)d_in[8];
    const float* fc1b   = (const float*)d_in[9];
    const float* fc2W   = (const float*)d_in[10];
    const float* fc2b   = (const float*)d_in[11];
    float* out = (float*)d_out;

    const int N = in_sizes[3];          // 50000 nodes
    const int E = in_sizes[2];          // 1600000 edges
    const int G = 64;
    const int* rows = eidx;
    const int* cols = eidx + E;
    const int NR = (N + NRANGE - 1) / NRANGE;
    const int RSEG = E / NRANGE + 2048;

    float* ws = (float*)d_ws;
    size_t off = 0;
    auto alloc = [&](size_t n) { float* p = ws + off; off += (n + 15) & ~(size_t)15; return p; };
    // --- zero-initialized region ---
    float*    sums     = alloc(64 * 64);
    float*    cntf     = alloc(16);
    int*      ovfcnt   = (int*)alloc(16);
    int*      rangeCnt = (int*)alloc(NRANGE);
    int*      cnt      = (int*)alloc(N);          // degree (exact)
    int*      wsum     = (int*)alloc(N);          // q15 weight sum -> dinv
    size_t zfloats = off;
    // --- rest ---
    unsigned short* wt1 = (unsigned short*)alloc(128 * KP / 2 + 16);
    unsigned short* wt2 = (unsigned short*)alloc(64 * KP / 2 + 16);
    unsigned* slot   = (unsigned*)alloc((size_t)N * CAP);
    int4*     ovf    = (int4*)alloc((size_t)OVFCAP * 4);
    float*    bufA   = alloc((size_t)N * 128);   // xw1f8 | xw2f8
    float*    bufB   = alloc((size_t)N * 128);   // rng | h(bf16)
    unsigned char*  xw1f8 = (unsigned char*)bufA;              // [2][N][64] fp8
    unsigned char*  xw2f8 = (unsigned char*)bufA;              // [1][N][64] fp8
    uint2*          rng   = (uint2*)bufB;                      // NRANGE*RSEG uint2, dead before h
    unsigned short* hbf   = (unsigned short*)bufB;             // [N][128] bf16
    (void)ws_size;

    hipMemsetAsync(d_ws, 0, zfloats * sizeof(float), stream);

    // CSR build (+ weight prep riding as 2 extra blocks on part)
    const bool fits = (NR <= MAXNRP) &&
                      ((size_t)NRANGE * RSEG * sizeof(uint2) <= (size_t)N * 512);
    if (fits) {
        part_kernel<<<PARTNB + 2, 512, 0, stream>>>(rows, cols, ew, rangeCnt, rng, E, NR, RSEG,
                                                    W1, W2, wt1, wt2);
        place_kernel<<<NRANGE, 512, 0, stream>>>(rng, rangeCnt, cnt, wsum, slot, ovf, ovfcnt,
                                                 NR, RSEG, N);
    } else {
        part_kernel<<<PARTNB + 2, 512, 0, stream>>>(rows, cols, ew, rangeCnt, rng, 0, NR, RSEG,
                                                    W1, W2, wt1, wt2);   // weights still prepped
        place_simple_kernel<<<(E + 255) / 256, 256, 0, stream>>>(rows, cols, ew, cnt, wsum,
                                                                 slot, ovf, ovfcnt, E);
    }

    // Layer 1: MFMA gemm (fp32 A) -> fp8 table (2 slices); gather -> h (bf16)
    gemm_mfma_kernel<128, true><<<(N + 63) / 64, 256, 0, stream>>>(x, wt1, wsum, xw1f8, N);
    gather_kernel<128, 2, true, false><<<((N + 15) / 16) * 2, 256, 0, stream>>>(
        xw1f8, slot, cnt, wsum, b1, ovf, ovfcnt, hbf, N, nullptr, nullptr, nullptr);

    // Layer 2: MFMA gemm (bf16 A = h) -> fp8 table (1 slice);
    // gather + fused mean-pool accumulation (x1 never materialized)
    gemm_mfma_kernel<64, false><<<(N + 63) / 64, 256, 0, stream>>>(hbf, wt2, wsum, xw2f8, N);
    gather_kernel<64, 1, false, true><<<(N + 15) / 16, 256, 0, stream>>>(
        xw2f8, slot, cnt, wsum, b2, ovf, ovfcnt, nullptr, N, batch, sums, cntf);

    head_kernel<<<G, 128, 0, stream>>>(sums, cntf, fc1W, fc1b, fc2W, fc2b, out);
}